// Round 6
// baseline (143.278 us; speedup 1.0000x reference)
//
#include <hip/hip_runtime.h>
#include <stdint.h>

// TypedLinear: out[i] = W[types[i]] @ x[i] + b[types[i]]
// N=65536, IN=OUT=256, T=8, fp32 in/out. bf16-MFMA, LOCAL per-block type sort.
// This rev: no global bucketing. Each block owns 128 CONSECUTIVE rows:
//   - x read contiguous, out written contiguous (no scattered HBM traffic)
//   - types counting-sorted in LDS; MFMA row-fragments gather rows from LDS
//   - per-type B fragments loaded from packed Wp adjacent to use
// 2 dispatches total (pack W, gemm). No memset / bucket / plan / idx.

#define NROWS 65536
#define NTYPES 8
#define KDIM 256
#define ODIM 256
#define RPB 128                  // rows per block
#define NBLK (NROWS / RPB)       // 512
#define MAXFRAG 16               // sum ceil(c_t/16) <= 8 + 7

typedef __attribute__((ext_vector_type(8))) short short8;
typedef __attribute__((ext_vector_type(4))) float f32x4;

__device__ __forceinline__ unsigned short f2bf(float f) {
    // round-to-nearest-even fp32 -> bf16
    unsigned int u = __float_as_uint(f);
    u += 0x7fffu + ((u >> 16) & 1u);
    return (unsigned short)(u >> 16);
}

// ---------------- pack W fp32 -> bf16 in MFMA-fragment order ----------------
// Wp[((t*16+f)*8+q)*512 + l*8 + e] = bf16(W[t][f*16+(l&15)][q*32+(l>>4)*8+e])
// Fully coalesced: thread gid reads 32B contiguous, writes one 16B record pair.
__global__ void prep_pack_kernel(const float* __restrict__ W,
                                 unsigned short* __restrict__ Wp) {
    const int gid = blockIdx.x * 256 + threadIdx.x;   // 0..65535
    const int R   = gid >> 5;                         // W row: t*256 + r
    const int c32 = gid & 31;                         // 8-float chunk of the row
    const int t  = R >> 8;
    const int r  = R & 255;
    const int f  = r >> 4;
    const int rr = r & 15;
    const int q  = c32 >> 2;
    const int l  = (c32 & 3) * 16 + rr;
    const float* src = W + (size_t)R * KDIM + c32 * 8;
    const float4 v0 = *(const float4*)src;
    const float4 v1 = *(const float4*)(src + 4);
    ushort4 p0, p1;
    p0.x = f2bf(v0.x); p0.y = f2bf(v0.y); p0.z = f2bf(v0.z); p0.w = f2bf(v0.w);
    p1.x = f2bf(v1.x); p1.y = f2bf(v1.y); p1.z = f2bf(v1.z); p1.w = f2bf(v1.w);
    ushort4* dst = (ushort4*)(Wp + (size_t)(((t * 16 + f) * 8 + q) * 512 + l * 8));
    dst[0] = p0; dst[1] = p1;
}

// ---------------- gemm with local type sort ----------------
// 256 threads = 4 waves; wave owns 64 output cols. As: [128 rows][256 k] bf16
// (64 KB), 16B-chunk XOR swizzle c' = c ^ (row&7). Rows stored in window order;
// per-type fragments pick rows via LDS perm.
__global__ __launch_bounds__(256, 2)
void gemm_kernel(const float* __restrict__ x,
                 const float* __restrict__ bias,
                 const unsigned short* __restrict__ Wp,
                 const int* __restrict__ types,
                 float* __restrict__ out) {
    const int w0 = blockIdx.x * RPB;

    __shared__ unsigned short As[RPB * KDIM];    // 64 KB, swizzled
    __shared__ int perm[RPB];
    __shared__ int hist[NTYPES];
    __shared__ int base_[NTYPES];
    __shared__ int ftype[MAXFRAG];
    __shared__ int fbase[MAXFRAG];
    __shared__ int fcnt_[MAXFRAG];
    __shared__ int nfrag_s;
    char* AsB = (char*)As;

    const int tid = threadIdx.x;

    if (tid < NTYPES) hist[tid] = 0;
    __syncthreads();

    // ---- types + local histogram (lanes 0..127), overlapped with A staging
    int myt = 0, myrank = 0;
    if (tid < RPB) {
        myt = types[w0 + tid];
        myrank = atomicAdd(&hist[myt], 1);
    }

    // ---- stage A: 128 rows x 256 fp32 -> bf16 LDS, contiguous reads.
    // 2 threads per row, each owns a 128-float k-half (32 float4).
    {
        const int srow = tid >> 1;               // 0..127
        const int sh   = tid & 1;                // k-half
        const float* xs = x + (size_t)(w0 + srow) * KDIM + sh * 128;
        #pragma unroll
        for (int rnd = 0; rnd < 4; ++rnd) {
            float4 av[8];
            #pragma unroll
            for (int s = 0; s < 8; ++s)
                av[s] = *(const float4*)(xs + (rnd * 8 + s) * 4);
            #pragma unroll
            for (int s = 0; s < 8; ++s) {
                const int slot = sh * 32 + rnd * 8 + s;   // float4 slot 0..63
                ushort4 pk;
                pk.x = f2bf(av[s].x); pk.y = f2bf(av[s].y);
                pk.z = f2bf(av[s].z); pk.w = f2bf(av[s].w);
                const int c = slot >> 1;                  // 16B chunk 0..31
                *(ushort4*)(AsB + srow * 512 + ((c ^ (srow & 7)) * 16)
                            + (slot & 1) * 8) = pk;
            }
        }
    }
    __syncthreads();   // hist complete

    // ---- prefix + fragment list (uniform, tiny)
    if (tid == 0) {
        int acc = 0, nf = 0;
        #pragma unroll
        for (int t2 = 0; t2 < NTYPES; ++t2) {
            base_[t2] = acc;
            const int c = hist[t2];
            for (int f = 0; f < c; f += 16) {
                ftype[nf] = t2;
                fbase[nf] = acc + f;
                fcnt_[nf] = (c - f < 16) ? (c - f) : 16;
                ++nf;
            }
            acc += c;
        }
        nfrag_s = nf;
    }
    __syncthreads();
    if (tid < RPB) perm[base_[myt] + myrank] = tid;   // local row id, type-sorted
    __syncthreads();

    const int wave = tid >> 6;       // 0..3, owns cols [wave*64, wave*64+64)
    const int lane = tid & 63;
    const int lr = lane & 15;
    const int lq = lane >> 4;
    const int nfrag = nfrag_s;

    short8 bf[8][4];
    float bv[4];
    int cur_t = -1;

    for (int fi = 0; fi < nfrag; ++fi) {
        const int t = ftype[fi];                 // block-uniform
        if (t != cur_t) {
            // load this type's 32 B fragments (adjacent to use; L2-resident)
            const unsigned short* wbase = Wp + (size_t)t * (16 * 8 * 512)
                                             + (size_t)(wave * 4) * 8 * 512 + lane * 8;
            #pragma unroll
            for (int q = 0; q < 8; ++q)
                #pragma unroll
                for (int j = 0; j < 4; ++j)
                    bf[q][j] = *(const short8*)(wbase + j * 4096 + q * 512);
            #pragma unroll
            for (int j = 0; j < 4; ++j)
                bv[j] = bias[t * ODIM + wave * 64 + j * 16 + lr];
            cur_t = t;
        }
        const int fb = fbase[fi], fc = fcnt_[fi];
        const int arow = perm[fb + (lr < fc ? lr : 0)];   // dup-pad short frags

        f32x4 acc[4] = {};
        #pragma unroll
        for (int q = 0; q < 8; ++q) {
            const short8 af = *(const short8*)(AsB + arow * 512
                                 + ((((q << 2) + lq) ^ (arow & 7)) * 16));
            #pragma unroll
            for (int j = 0; j < 4; ++j)
                acc[j] = __builtin_amdgcn_mfma_f32_16x16x32_bf16(
                    af, bf[q][j], acc[j], 0, 0, 0);
        }

        // epilogue: D col = lane&15, frag-row = lq*4 + r; rows in-window
        #pragma unroll
        for (int r = 0; r < 4; ++r) {
            const int fr = lq * 4 + r;
            if (fr < fc) {
                const size_t orow = (size_t)(w0 + perm[fb + fr]) * ODIM;
                #pragma unroll
                for (int j = 0; j < 4; ++j)
                    out[orow + wave * 64 + j * 16 + lr] = acc[j][r] + bv[j];
            }
        }
    }
}

extern "C" void kernel_launch(void* const* d_in, const int* in_sizes, int n_in,
                              void* d_out, int out_size, void* d_ws, size_t ws_size,
                              hipStream_t stream) {
    const float* x     = (const float*)d_in[0];
    const int*   types = (const int*)d_in[1];
    const float* W     = (const float*)d_in[2];
    const float* b     = (const float*)d_in[3];
    float* out = (float*)d_out;

    // ws: just the packed bf16 W (1 MB)
    unsigned short* Wp = (unsigned short*)d_ws;

    prep_pack_kernel<<<256, 256, 0, stream>>>(W, Wp);
    gemm_kernel<<<NBLK, 256, 0, stream>>>(x, b, Wp, types, out);
}